// Round 2
// baseline (783.119 us; speedup 1.0000x reference)
//
#include <hip/hip_runtime.h>
#include <stdint.h>
#include <math.h>

#define THREADS 256
#define NBINS 65536
#define CANDCAP 8128
#define NEGV (-1e30f)
#define NLEV 15   // qw,qh in [-5, 9]

struct GridCfg {
    int prefX[NLEV], prefY[NLEV], nx[NLEV], ny[NLEV];
    int totY;
};

__device__ __forceinline__ uint32_t f2ord(float f) {
    uint32_t u = __float_as_uint(f);
    return (u & 0x80000000u) ? ~u : (u | 0x80000000u);
}
__device__ __forceinline__ float ord2f(uint32_t u) {
    uint32_t b = (u & 0x80000000u) ? (u ^ 0x80000000u) : ~u;
    return __uint_as_float(b);
}

// Compute the perfect-hash cell for one (box, offset). Math must bit-match the
// reference: f32 ops, no FMA contraction, correctly-rounded log/pow via double.
__device__ __forceinline__ uint64_t cell_of(float cx, float cy, float Lw, float Lh,
                                            float dw, float dh, float dx, float dy,
                                            const float* __restrict__ powtab,
                                            const GridCfg g) {
#pragma clang fp contract(off)
    float qw = floorf(Lw + dw);
    float qh = floorf(Lh + dh);
    int iw = (int)qw, ih = (int)qh;
    int t = iw + 5; t = t < 0 ? 0 : (t > NLEV - 1 ? NLEV - 1 : t);
    int u = ih + 5; u = u < 0 ? 0 : (u > NLEV - 1 ? NLEV - 1 : u);
    float cellx = 9.6f * powtab[t];   // alpha*w0 = f32(9.6) * f32 pow(1.4,qw)
    float celly = 9.6f * powtab[u];
    float qx = floorf(cx / cellx + dx);
    float qy = floorf(cy / celly + dy);
    int ix = (int)qx, iy = (int)qy;
    ix = ix < 0 ? 0 : (ix > g.nx[t] - 1 ? g.nx[t] - 1 : ix);
    iy = iy < 0 ? 0 : (iy > g.ny[u] - 1 ? g.ny[u] - 1 : iy);
    return (uint64_t)(g.prefX[t] + ix) * (uint64_t)g.totY + (uint64_t)(g.prefY[u] + iy);
}

__device__ __forceinline__ void load_tabs(const float* __restrict__ offs, int num_off,
                                          float* powtab, float* soff) {
    int t = threadIdx.x;
    if (t < NLEV) powtab[t] = (float)pow((double)1.4f, (double)(t - 5));
    if (t >= 32 && t - 32 < num_off * 4) soff[t - 32] = offs[t - 32];
    __syncthreads();
}

// ---- insert: one fire-and-forget 64-bit atomicMax per (box, offset). ----
// xor_mask: stage1 = 0x80000000 (clears MSB of ord since s in [0,1)),
//           stage2 = 0 (kept boxes have ord MSB=1 -> beat stale stage1 entries).
__global__ void k_insert(const float4* __restrict__ rects,
                         const float* __restrict__ svals,
                         const float* __restrict__ offs, int num_off,
                         uint64_t* __restrict__ vals,
                         int N, GridCfg g, uint64_t tot, uint32_t xor_mask) {
#pragma clang fp contract(off)
    __shared__ float powtab[NLEV];
    __shared__ float soff[16];
    load_tabs(offs, num_off, powtab, soff);
    int i = blockIdx.x * blockDim.x + threadIdx.x;
    if (i >= N) return;

    float4 r = rects[i];
    float s = svals[i];
    uint64_t packed = ((uint64_t)(f2ord(s) ^ xor_mask) << 32) | (uint32_t)(~(uint32_t)i);

    const float lg = (float)log((double)1.4f);
    float Lw = (float)log((double)(r.z * 0.0625f)) / lg;
    float Lh = (float)log((double)(r.w * 0.0625f)) / lg;

    for (int k = 0; k < num_off; ++k) {
        uint64_t c = cell_of(r.x, r.y, Lw, Lh,
                             soff[k * 4 + 0], soff[k * 4 + 1],
                             soff[k * 4 + 2], soff[k * 4 + 3], powtab, g);
        atomicMax((unsigned long long*)&vals[(uint64_t)k * tot + c],
                  (unsigned long long)packed);
    }
}

// ---- stage1 resolve: keep iff winner of every bucket; mscore = keep?s:NEG ----
__global__ void k_resolve1(const float4* __restrict__ rects,
                           const float* __restrict__ scores,
                           const float* __restrict__ offs, int num_off,
                           const uint64_t* __restrict__ vals,
                           float* __restrict__ mscore,
                           int N, GridCfg g, uint64_t tot) {
#pragma clang fp contract(off)
    __shared__ float powtab[NLEV];
    __shared__ float soff[16];
    load_tabs(offs, num_off, powtab, soff);
    int i = blockIdx.x * blockDim.x + threadIdx.x;
    if (i >= N) return;

    float4 r = rects[i];
    const float lg = (float)log((double)1.4f);
    float Lw = (float)log((double)(r.z * 0.0625f)) / lg;
    float Lh = (float)log((double)(r.w * 0.0625f)) / lg;

    bool keep = true;
    for (int k = 0; k < num_off; ++k) {
        uint64_t c = cell_of(r.x, r.y, Lw, Lh,
                             soff[k * 4 + 0], soff[k * 4 + 1],
                             soff[k * 4 + 2], soff[k * 4 + 3], powtab, g);
        uint64_t v = vals[(uint64_t)k * tot + c];
        keep = keep && ((~(uint32_t)v) == (uint32_t)i);
    }
    mscore[i] = keep ? scores[i] : NEGV;
}

// ---- stage2 resolve: IoU vs bucket representative; combine; histogram. ----
__global__ void k_resolve2(const float4* __restrict__ rects,
                           const float* __restrict__ scores,
                           const float* __restrict__ mscore,
                           const float* __restrict__ offs, int num_off,
                           const uint64_t* __restrict__ vals,
                           float* __restrict__ finals,
                           uint32_t* __restrict__ hist,
                           int N, GridCfg g, uint64_t tot) {
#pragma clang fp contract(off)
    __shared__ float powtab[NLEV];
    __shared__ float soff[16];
    load_tabs(offs, num_off, powtab, soff);
    int i = blockIdx.x * blockDim.x + threadIdx.x;
    if (i >= N) return;

    float4 a = rects[i];
    bool keep = (mscore[i] >= 0.0f);   // keep1 (NEG means killed in stage 1)
    if (keep) {
        const float lg = (float)log((double)1.4f);
        float Lw = (float)log((double)(a.z * 0.0625f)) / lg;
        float Lh = (float)log((double)(a.w * 0.0625f)) / lg;
        for (int k = 0; k < num_off && keep; ++k) {
            uint64_t c = cell_of(a.x, a.y, Lw, Lh,
                                 soff[k * 4 + 0], soff[k * 4 + 1],
                                 soff[k * 4 + 2], soff[k * 4 + 3], powtab, g);
            uint64_t v = vals[(uint64_t)k * tot + c];
            uint32_t rep = ~(uint32_t)v;
            if (rep != (uint32_t)i) {
                float4 b = rects[rep];
                float ax1 = a.x - 0.5f * a.z, ay1 = a.y - 0.5f * a.w;
                float ax2 = a.x + 0.5f * a.z, ay2 = a.y + 0.5f * a.w;
                float bx1 = b.x - 0.5f * b.z, by1 = b.y - 0.5f * b.w;
                float bx2 = b.x + 0.5f * b.z, by2 = b.y + 0.5f * b.w;
                float iw = fminf(ax2, bx2) - fmaxf(ax1, bx1); iw = fmaxf(iw, 0.0f);
                float ih = fminf(ay2, by2) - fmaxf(ay1, by1); ih = fmaxf(ih, 0.0f);
                float inter = iw * ih;
                float uni = a.z * a.w + b.z * b.w - inter;
                float iou = inter / fmaxf(uni, 1e-12f);
                keep = keep && (iou <= 0.5f);
            }
        }
    }
    float s = scores[i];
    finals[i] = keep ? s : NEGV;
    if (keep) {
        int b = (int)(s * 65536.0f);
        b = b < 0 ? 0 : (b > NBINS - 1 ? NBINS - 1 : b);
        atomicAdd(&hist[b], 1u);
    }
}

// ---- threshold bin: largest T with count(bin >= T) >= K ----
__global__ void k_thresh(const uint32_t* __restrict__ hist, int* scalars, int K) {
    __shared__ uint32_t sh[1024];
    __shared__ int tmax;
    __shared__ uint32_t running_s;
    int t = threadIdx.x;
    if (t == 0) { running_s = 0; scalars[0] = 0; }
    __syncthreads();
    for (int base = NBINS - 1024; base >= 0; base -= 1024) {
        if (t == 0) tmax = -1;
        sh[t] = hist[base + t];
        __syncthreads();
        for (int off = 1; off < 1024; off <<= 1) {
            uint32_t v = (t + off < 1024) ? sh[t + off] : 0u;
            __syncthreads();
            sh[t] += v;
            __syncthreads();
        }
        if (running_s + sh[t] >= (uint32_t)K) atomicMax(&tmax, t);
        __syncthreads();
        if (tmax >= 0) {
            if (t == 0) scalars[0] = base + tmax;
            return;
        }
        if (t == 0) running_s += sh[0];
        __syncthreads();
    }
}

// ---- compact candidates above threshold bin ----
__global__ void k_compact(const float* __restrict__ finals,
                          uint64_t* __restrict__ cand, int* scalars, int N) {
    int i = blockIdx.x * blockDim.x + threadIdx.x;
    if (i >= N) return;
    float v = finals[i];
    if (v >= 0.0f) {
        int b = (int)(v * 65536.0f);
        b = b < 0 ? 0 : (b > NBINS - 1 ? NBINS - 1 : b);
        if (b >= scalars[0]) {
            int pos = atomicAdd(&scalars[1], 1);
            if (pos < CANDCAP)
                cand[pos] = ((uint64_t)f2ord(v) << 32) | (uint32_t)(~(uint32_t)i);
        }
    }
}

// ---- exact rank (value desc, idx asc), emit [rects[idx], val] rows ----
__global__ void k_topk(const float4* __restrict__ rects,
                       const uint64_t* __restrict__ cand,
                       const int* __restrict__ scalars,
                       float* __restrict__ out, int K) {
    __shared__ uint64_t sc[CANDCAP];
    int t = threadIdx.x;
    int M = scalars[1]; if (M > CANDCAP) M = CANDCAP;
    for (int j = t; j < M; j += blockDim.x) sc[j] = cand[j];
    __syncthreads();
    for (int j = t; j < M; j += blockDim.x) {
        uint64_t me = sc[j];
        int rank = 0;
        for (int k = 0; k < M; ++k) rank += (sc[k] > me) ? 1 : 0;
        if (rank < K) {
            uint32_t idx = ~(uint32_t)me;
            float v = ord2f((uint32_t)(me >> 32));
            float4 r = rects[idx];
            float* o = out + (size_t)rank * 5;
            o[0] = r.x; o[1] = r.y; o[2] = r.z; o[3] = r.w; o[4] = v;
        }
    }
}

extern "C" void kernel_launch(void* const* d_in, const int* in_sizes, int n_in,
                              void* d_out, int out_size, void* d_ws, size_t ws_size,
                              hipStream_t stream) {
    const float4* rects = (const float4*)d_in[0];
    const float* scores = (const float*)d_in[1];
    const float* off1 = (const float*)d_in[2];
    const float* off2 = (const float*)d_in[3];
    int N = in_sizes[0] / 4;
    int num1 = in_sizes[2] / 4;
    int num2 = in_sizes[3] / 4;
    int NT = num1 > num2 ? num1 : num2;
    int K = out_size / 5;
    float* out = (float*)d_out;

    // Build the multilevel grid config (host doubles; used only for sizing /
    // injective layout, identical struct passed to every kernel).
    GridCfg g;
    int px = 0, py = 0;
    for (int q = 0; q < NLEV; ++q) {
        double cell = 9.6 * pow(1.4, (double)(q - 5));
        int nx = (int)floor(1333.0 / cell) + 2;   // qx = floor(cx/cell+dx) <= floor(1333/cell)+1
        int ny = (int)floor(800.0 / cell) + 2;
        g.nx[q] = nx; g.ny[q] = ny;
        g.prefX[q] = px; g.prefY[q] = py;
        px += nx; py += ny;
    }
    g.totY = py;
    uint64_t TOT = (uint64_t)px * (uint64_t)py;   // ~4.15M cells

    char* p = (char*)d_ws;
    uint64_t* vals = (uint64_t*)p; p += (size_t)NT * TOT * 8;
    uint32_t* hist = (uint32_t*)p; p += (size_t)NBINS * 4;
    int* scalars   = (int*)p;      p += 256;
    uint64_t* cand = (uint64_t*)p; p += (size_t)CANDCAP * 8;
    float* mscore  = (float*)p;    p += (size_t)N * 4;
    float* finals  = (float*)p;

    size_t tblBytes = (size_t)NT * TOT * 8;
    int blocks = (N + THREADS - 1) / THREADS;

    // one zero-init covers tables + hist + scalars (contiguous).
    hipMemsetAsync(vals, 0, tblBytes + (size_t)NBINS * 4 + 256, stream);

    // stage 1: packed has MSB=0 (ord ^ 0x80000000, valid since s in [0,1))
    k_insert<<<blocks, THREADS, 0, stream>>>(rects, scores, off1, num1, vals,
                                             N, g, TOT, 0x80000000u);
    k_resolve1<<<blocks, THREADS, 0, stream>>>(rects, scores, off1, num1, vals,
                                               mscore, N, g, TOT);

    // stage 2 reuses the tables WITHOUT clearing: kept boxes' packed values
    // have MSB=1 and beat any stale stage-1 entry; stale winners only affect
    // keep2 of boxes with keep1=false, which the final AND discards.
    k_insert<<<blocks, THREADS, 0, stream>>>(rects, mscore, off2, num2, vals,
                                             N, g, TOT, 0u);
    k_resolve2<<<blocks, THREADS, 0, stream>>>(rects, scores, mscore, off2, num2,
                                               vals, finals, hist, N, g, TOT);

    // top-k
    k_thresh<<<1, 1024, 0, stream>>>(hist, scalars, K);
    k_compact<<<blocks, THREADS, 0, stream>>>(finals, cand, scalars, N);
    k_topk<<<1, 1024, 0, stream>>>(rects, cand, scalars, out, K);
}

// Round 3
// 296.295 us; speedup vs baseline: 2.6430x; 2.6430x over previous
//
#include <hip/hip_runtime.h>
#include <stdint.h>
#include <math.h>

#define THREADS 256
#define NBINS 65536
#define CANDCAP 8128
#define NEGV (-1e30f)
#define NLEV 15   // qw,qh in [-5, 9]
#define ODDMULT 0x9E3779B1u

struct GridCfg {
    int prefX[NLEV], prefY[NLEV], nx[NLEV], ny[NLEV];
    int totY;
};

__device__ __forceinline__ uint32_t f2ord(float f) {
    uint32_t u = __float_as_uint(f);
    return (u & 0x80000000u) ? ~u : (u | 0x80000000u);
}
__device__ __forceinline__ float ord2f(uint32_t u) {
    uint32_t b = (u & 0x80000000u) ? (u ^ 0x80000000u) : ~u;
    return __uint_as_float(b);
}

// Perfect-hash cell for one (box, offset). Must bit-match the reference:
// f32 ops, no FMA contraction, correctly-rounded log/pow via double.
__device__ __forceinline__ uint32_t cell_of(float cx, float cy, float Lw, float Lh,
                                            float dw, float dh, float dx, float dy,
                                            const float* __restrict__ powtab,
                                            const GridCfg g) {
#pragma clang fp contract(off)
    float qw = floorf(Lw + dw);
    float qh = floorf(Lh + dh);
    int iw = (int)qw, ih = (int)qh;
    int t = iw + 5; t = t < 0 ? 0 : (t > NLEV - 1 ? NLEV - 1 : t);
    int u = ih + 5; u = u < 0 ? 0 : (u > NLEV - 1 ? NLEV - 1 : u);
    float cellx = 9.6f * powtab[t];
    float celly = 9.6f * powtab[u];
    float qx = floorf(cx / cellx + dx);
    float qy = floorf(cy / celly + dy);
    int ix = (int)qx, iy = (int)qy;
    ix = ix < 0 ? 0 : (ix > g.nx[t] - 1 ? g.nx[t] - 1 : ix);
    iy = iy < 0 ? 0 : (iy > g.ny[u] - 1 ? g.ny[u] - 1 : iy);
    return (uint32_t)((g.prefX[t] + ix) * g.totY + (g.prefY[u] + iy));
}

__device__ __forceinline__ void load_tabs(const float* __restrict__ offs, int num_off,
                                          float* powtab, float* soff) {
    int t = threadIdx.x;
    if (t < NLEV) powtab[t] = (float)pow((double)1.4f, (double)(t - 5));
    if (t >= 32 && t - 32 < num_off * 4) soff[t - 32] = offs[t - 32];
    __syncthreads();
}

// ---- insert: read-filter + 64-bit atomicMax per (box, offset). ----
// Stage 1: xor_mask=0x80000000 (ord MSB cleared, since s in [0,1)).
// Stage 2: xor_mask=0, and svals<0 (killed boxes) skip entirely — any bucket
// that matters contains a kept box whose MSB=1 value beats stale stage-1 data.
__global__ void k_insert(const float4* __restrict__ rects,
                         const float* __restrict__ svals,
                         const float* __restrict__ offs, int num_off,
                         uint64_t* __restrict__ vals,
                         int N, GridCfg g, uint32_t slots, uint32_t mult,
                         uint32_t smask, uint32_t xor_mask) {
#pragma clang fp contract(off)
    __shared__ float powtab[NLEV];
    __shared__ float soff[16];
    load_tabs(offs, num_off, powtab, soff);
    int i = blockIdx.x * blockDim.x + threadIdx.x;
    if (i >= N) return;

    float s = svals[i];
    if (s < 0.0f) return;   // stage-2 killed boxes: no insert needed
    float4 r = rects[i];
    uint64_t packed = ((uint64_t)(f2ord(s) ^ xor_mask) << 32) | (uint32_t)(~(uint32_t)i);

    const float lg = (float)log((double)1.4f);
    float Lw = (float)log((double)(r.z * 0.0625f)) / lg;
    float Lh = (float)log((double)(r.w * 0.0625f)) / lg;

    uint32_t sl[8];
    for (int k = 0; k < num_off; ++k) {
        uint32_t c = cell_of(r.x, r.y, Lw, Lh,
                             soff[k * 4 + 0], soff[k * 4 + 1],
                             soff[k * 4 + 2], soff[k * 4 + 3], powtab, g);
        sl[k] = (c * mult) & smask;
    }
    uint64_t cur[8];
    for (int k = 0; k < num_off; ++k)
        cur[k] = vals[(uint64_t)k * slots + sl[k]];
    for (int k = 0; k < num_off; ++k)
        if (cur[k] < packed)
            atomicMax((unsigned long long*)&vals[(uint64_t)k * slots + sl[k]],
                      (unsigned long long)packed);
}

// ---- stage1 resolve: keep iff winner of every bucket; mscore = keep?s:NEG ----
__global__ void k_resolve1(const float4* __restrict__ rects,
                           const float* __restrict__ scores,
                           const float* __restrict__ offs, int num_off,
                           const uint64_t* __restrict__ vals,
                           float* __restrict__ mscore,
                           int N, GridCfg g, uint32_t slots, uint32_t mult,
                           uint32_t smask) {
#pragma clang fp contract(off)
    __shared__ float powtab[NLEV];
    __shared__ float soff[16];
    load_tabs(offs, num_off, powtab, soff);
    int i = blockIdx.x * blockDim.x + threadIdx.x;
    if (i >= N) return;

    float4 r = rects[i];
    const float lg = (float)log((double)1.4f);
    float Lw = (float)log((double)(r.z * 0.0625f)) / lg;
    float Lh = (float)log((double)(r.w * 0.0625f)) / lg;

    bool keep = true;
    for (int k = 0; k < num_off; ++k) {
        uint32_t c = cell_of(r.x, r.y, Lw, Lh,
                             soff[k * 4 + 0], soff[k * 4 + 1],
                             soff[k * 4 + 2], soff[k * 4 + 3], powtab, g);
        uint64_t v = vals[(uint64_t)k * slots + ((c * mult) & smask)];
        keep = keep && ((~(uint32_t)v) == (uint32_t)i);
    }
    mscore[i] = keep ? scores[i] : NEGV;
}

// ---- stage2 resolve: IoU vs bucket representative; combine; histogram. ----
__global__ void k_resolve2(const float4* __restrict__ rects,
                           const float* __restrict__ scores,
                           const float* __restrict__ mscore,
                           const float* __restrict__ offs, int num_off,
                           const uint64_t* __restrict__ vals,
                           float* __restrict__ finals,
                           uint32_t* __restrict__ hist,
                           int N, GridCfg g, uint32_t slots, uint32_t mult,
                           uint32_t smask) {
#pragma clang fp contract(off)
    __shared__ float powtab[NLEV];
    __shared__ float soff[16];
    load_tabs(offs, num_off, powtab, soff);
    int i = blockIdx.x * blockDim.x + threadIdx.x;
    if (i >= N) return;

    if (mscore[i] < 0.0f) { finals[i] = NEGV; return; }   // killed in stage 1

    float4 a = rects[i];
    const float lg = (float)log((double)1.4f);
    float Lw = (float)log((double)(a.z * 0.0625f)) / lg;
    float Lh = (float)log((double)(a.w * 0.0625f)) / lg;
    bool keep = true;
    for (int k = 0; k < num_off && keep; ++k) {
        uint32_t c = cell_of(a.x, a.y, Lw, Lh,
                             soff[k * 4 + 0], soff[k * 4 + 1],
                             soff[k * 4 + 2], soff[k * 4 + 3], powtab, g);
        uint64_t v = vals[(uint64_t)k * slots + ((c * mult) & smask)];
        uint32_t rep = ~(uint32_t)v;
        if (rep != (uint32_t)i) {
            float4 b = rects[rep];
            float ax1 = a.x - 0.5f * a.z, ay1 = a.y - 0.5f * a.w;
            float ax2 = a.x + 0.5f * a.z, ay2 = a.y + 0.5f * a.w;
            float bx1 = b.x - 0.5f * b.z, by1 = b.y - 0.5f * b.w;
            float bx2 = b.x + 0.5f * b.z, by2 = b.y + 0.5f * b.w;
            float iw = fminf(ax2, bx2) - fmaxf(ax1, bx1); iw = fmaxf(iw, 0.0f);
            float ih = fminf(ay2, by2) - fmaxf(ay1, by1); ih = fmaxf(ih, 0.0f);
            float inter = iw * ih;
            float uni = a.z * a.w + b.z * b.w - inter;
            float iou = inter / fmaxf(uni, 1e-12f);
            keep = keep && (iou <= 0.5f);
        }
    }
    float s = scores[i];
    finals[i] = keep ? s : NEGV;
    if (keep) {
        int b = (int)(s * 65536.0f);
        b = b < 0 ? 0 : (b > NBINS - 1 ? NBINS - 1 : b);
        atomicAdd(&hist[b], 1u);
    }
}

// ---- threshold bin: largest T with count(bin >= T) >= K ----
__global__ void k_thresh(const uint32_t* __restrict__ hist, int* scalars, int K) {
    __shared__ uint32_t sh[1024];
    __shared__ int tmax;
    __shared__ uint32_t running_s;
    int t = threadIdx.x;
    if (t == 0) { running_s = 0; scalars[0] = 0; }
    __syncthreads();
    for (int base = NBINS - 1024; base >= 0; base -= 1024) {
        if (t == 0) tmax = -1;
        sh[t] = hist[base + t];
        __syncthreads();
        for (int off = 1; off < 1024; off <<= 1) {
            uint32_t v = (t + off < 1024) ? sh[t + off] : 0u;
            __syncthreads();
            sh[t] += v;
            __syncthreads();
        }
        if (running_s + sh[t] >= (uint32_t)K) atomicMax(&tmax, t);
        __syncthreads();
        if (tmax >= 0) {
            if (t == 0) scalars[0] = base + tmax;
            return;
        }
        if (t == 0) running_s += sh[0];
        __syncthreads();
    }
}

// ---- compact candidates above threshold bin ----
__global__ void k_compact(const float* __restrict__ finals,
                          uint64_t* __restrict__ cand, int* scalars, int N) {
    int i = blockIdx.x * blockDim.x + threadIdx.x;
    if (i >= N) return;
    float v = finals[i];
    if (v >= 0.0f) {
        int b = (int)(v * 65536.0f);
        b = b < 0 ? 0 : (b > NBINS - 1 ? NBINS - 1 : b);
        if (b >= scalars[0]) {
            int pos = atomicAdd(&scalars[1], 1);
            if (pos < CANDCAP)
                cand[pos] = ((uint64_t)f2ord(v) << 32) | (uint32_t)(~(uint32_t)i);
        }
    }
}

// ---- exact rank (value desc, idx asc), emit [rects[idx], val] rows ----
__global__ void k_topk(const float4* __restrict__ rects,
                       const uint64_t* __restrict__ cand,
                       const int* __restrict__ scalars,
                       float* __restrict__ out, int K) {
    __shared__ uint64_t sc[CANDCAP];
    int t = threadIdx.x;
    int M = scalars[1]; if (M > CANDCAP) M = CANDCAP;
    for (int j = t; j < M; j += blockDim.x) sc[j] = cand[j];
    __syncthreads();
    for (int j = t; j < M; j += blockDim.x) {
        uint64_t me = sc[j];
        int rank = 0;
        for (int k = 0; k < M; ++k) rank += (sc[k] > me) ? 1 : 0;
        if (rank < K) {
            uint32_t idx = ~(uint32_t)me;
            float v = ord2f((uint32_t)(me >> 32));
            float4 r = rects[idx];
            float* o = out + (size_t)rank * 5;
            o[0] = r.x; o[1] = r.y; o[2] = r.z; o[3] = r.w; o[4] = v;
        }
    }
}

extern "C" void kernel_launch(void* const* d_in, const int* in_sizes, int n_in,
                              void* d_out, int out_size, void* d_ws, size_t ws_size,
                              hipStream_t stream) {
    const float4* rects = (const float4*)d_in[0];
    const float* scores = (const float*)d_in[1];
    const float* off1 = (const float*)d_in[2];
    const float* off2 = (const float*)d_in[3];
    int N = in_sizes[0] / 4;
    int num1 = in_sizes[2] / 4;
    int num2 = in_sizes[3] / 4;
    int NT = num1 > num2 ? num1 : num2;
    int K = out_size / 5;
    float* out = (float*)d_out;

    GridCfg g;
    int px = 0, py = 0;
    for (int q = 0; q < NLEV; ++q) {
        double cell = 9.6 * pow(1.4, (double)(q - 5));
        int nx = (int)floor(1333.0 / cell) + 2;
        int ny = (int)floor(800.0 / cell) + 2;
        g.nx[q] = nx; g.ny[q] = ny;
        g.prefX[q] = px; g.prefY[q] = py;
        px += nx; py += ny;
    }
    g.totY = py;
    uint64_t TOT = (uint64_t)px * (uint64_t)py;   // ~4.14M cells

    // Injective scatter: cell * odd (mod 2^22) is a bijection; valid while
    // TOT <= 2^22. Spreads hot coarse-level cells across all L2 channels.
    uint32_t slots, mult, smask;
    if (TOT <= (1u << 22)) {
        slots = 1u << 22; mult = ODDMULT; smask = slots - 1;
    } else {
        slots = (uint32_t)TOT; mult = 1u; smask = 0xFFFFFFFFu;
    }

    char* p = (char*)d_ws;
    uint64_t* vals = (uint64_t*)p; p += (size_t)NT * slots * 8;
    uint32_t* hist = (uint32_t*)p; p += (size_t)NBINS * 4;
    int* scalars   = (int*)p;      p += 256;
    uint64_t* cand = (uint64_t*)p; p += (size_t)CANDCAP * 8;
    float* mscore  = (float*)p;    p += (size_t)N * 4;
    float* finals  = (float*)p;

    size_t tblBytes = (size_t)NT * slots * 8;
    int blocks = (N + THREADS - 1) / THREADS;

    // one zero-init covers tables + hist + scalars (contiguous)
    hipMemsetAsync(vals, 0, tblBytes + (size_t)NBINS * 4 + 256, stream);

    // stage 1 (ord MSB cleared -> all stage-1 entries lose to stage-2 ones)
    k_insert<<<blocks, THREADS, 0, stream>>>(rects, scores, off1, num1, vals,
                                             N, g, slots, mult, smask, 0x80000000u);
    k_resolve1<<<blocks, THREADS, 0, stream>>>(rects, scores, off1, num1, vals,
                                               mscore, N, g, slots, mult, smask);

    // stage 2: tables reused WITHOUT clearing (epoch trick); killed boxes skip
    k_insert<<<blocks, THREADS, 0, stream>>>(rects, mscore, off2, num2, vals,
                                             N, g, slots, mult, smask, 0u);
    k_resolve2<<<blocks, THREADS, 0, stream>>>(rects, scores, mscore, off2, num2,
                                               vals, finals, hist, N, g, slots,
                                               mult, smask);

    // top-k
    k_thresh<<<1, 1024, 0, stream>>>(hist, scalars, K);
    k_compact<<<blocks, THREADS, 0, stream>>>(finals, cand, scalars, N);
    k_topk<<<1, 1024, 0, stream>>>(rects, cand, scalars, out, K);
}